// Round 4
// baseline (328.365 us; speedup 1.0000x reference)
//
#include <hip/hip_runtime.h>

// RoPE2D cos/sin table generator — float32.
// Output: [cos_2d (rows*dim)] ++ [sin_2d (rows*dim)], rows = H*W, dim = dimx+dimy.
// Row p = y*W + x. Channel c:
//   c in [0, dimx):   ang = x * ifx[c mod (dimx/2)]
//   c in [dimx, dim): ang = y * ify[(c-dimx) mod (dimy/2)]
// Fast path: one thread = 4 channels of one row, emits BOTH the cos and the sin
// dwordx4 (sin half shares identical (p,ch,angle) at offset +rows*dim).
// Every store instruction is lane-dense (64 lanes x 16 B = 1 KB contiguous).

typedef __attribute__((ext_vector_type(4))) float float4v;

// dimx = dimy = 64 (dim = 128, half-tables of 32; fidx = ch & 31 in both halves).
__global__ __launch_bounds__(256) void rope2d_fast(
    const float* __restrict__ ifx,
    const float* __restrict__ ify,
    const int* __restrict__ wptr,
    float* __restrict__ out,
    int rows)
{
    const int idx = blockIdx.x * blockDim.x + threadIdx.x;
    const int nvec = rows << 5;              // rows*128/4 vec4 slots in cos half
    if (idx >= nvec) return;

    const int e  = idx << 2;                 // element offset within cos half
    const int p  = idx >> 5;                 // row (e >> 7)
    const int ch = e & 127;                  // first channel of the vec4 (4-aligned)
    const int half = rows << 7;              // rows*128 elements

    const int W = *wptr;                     // uniform, L2-resident
    int xw, yh;
    if ((W & (W - 1)) == 0) {                // pow2 fast path (W=512)
        const int s = __ffs(W) - 1;
        xw = p & (W - 1);
        yh = p >> s;
    } else {
        xw = p % W;
        yh = p / W;
    }

    // channel quadrant: [0,64) -> x-table, [64,128) -> y-table; fidx = ch & 31
    const bool use_x = ch < 64;
    const float pos = use_x ? (float)xw : (float)yh;
    const float* tab = use_x ? ifx : ify;
    const float4v fr = *reinterpret_cast<const float4v*>(tab + (ch & 31));

    float4v c, s;
#pragma unroll
    for (int i = 0; i < 4; ++i) {
        const float ang = pos * fr[i];       // |ang| <= 511 rad, within v_sin range
        c[i] = __cosf(ang);
        s[i] = __sinf(ang);
    }

    *reinterpret_cast<float4v*>(out + e)        = c;   // cos half, dense dwordx4
    *reinterpret_cast<float4v*>(out + half + e) = s;   // sin half, dense dwordx4
}

// Generic path: arbitrary dimx/dimy (scalar per element pair).
__global__ __launch_bounds__(256) void rope2d_generic(
    const float* __restrict__ ifx,
    const float* __restrict__ ify,
    const int* __restrict__ wptr,
    float* __restrict__ out,
    int rows, int dimx, int dimy)
{
    const int dim = dimx + dimy;
    const long long halfo = (long long)rows * dim;
    const long long e = (long long)(blockIdx.x * blockDim.x + threadIdx.x);
    if (e >= halfo) return;

    const int p  = (int)(e / dim);
    const int ch = (int)(e % dim);

    const int W = *wptr;
    const int xw = p % W, yh = p / W;

    float pos, f;
    if (ch < dimx) { pos = (float)xw; f = ifx[ch % (dimx >> 1)]; }
    else           { pos = (float)yh; f = ify[(ch - dimx) % (dimy >> 1)]; }
    const float ang = pos * f;
    out[e]         = __cosf(ang);
    out[halfo + e] = __sinf(ang);
}

extern "C" void kernel_launch(void* const* d_in, const int* in_sizes, int n_in,
                              void* d_out, int out_size, void* d_ws, size_t ws_size,
                              hipStream_t stream) {
    // inputs: [0]=x (f32, dtype-only), [1]=inv_freq_x (f32), [2]=inv_freq_y (f32),
    //         [3]=height (int32), [4]=width (int32)
    const float* ifx = (const float*)d_in[1];
    const float* ify = (const float*)d_in[2];
    const int* wptr  = (const int*)d_in[4];
    float* out = (float*)d_out;

    const int dimx = 2 * in_sizes[1];      // 64
    const int dimy = 2 * in_sizes[2];      // 64
    const int dim  = dimx + dimy;          // 128
    const int rows = in_sizes[0] / dim;    // H*W = 262144

    if (dimx == 64 && dimy == 64) {
        const int nvec = rows << 5;                        // 8,388,608 threads
        const int block = 256;
        const int grid = (nvec + block - 1) / block;       // 32,768 blocks
        rope2d_fast<<<grid, block, 0, stream>>>(ifx, ify, wptr, out, rows);
    } else {
        const long long halfo = (long long)rows * dim;
        const int block = 256;
        const int grid = (int)((halfo + block - 1) / block);
        rope2d_generic<<<grid, block, 0, stream>>>(ifx, ify, wptr, out, rows, dimx, dimy);
    }
}